// Round 9
// baseline (491.348 us; speedup 1.0000x reference)
//
#include <hip/hip_runtime.h>

typedef __bf16 bf16;
typedef bf16 bf16x8 __attribute__((ext_vector_type(8)));
typedef bf16 bf16x4 __attribute__((ext_vector_type(4)));
typedef short short4v __attribute__((ext_vector_type(4)));
typedef float f32x4 __attribute__((ext_vector_type(4)));

#define NPIX 196
#define CIN 384
#define NHEADS 12
#define MPAD 224
#define VSTRIDE 232   // LDS row stride for V (bf16): ~2-way banks
#define OSTRIDE 40    // LDS row stride for store-transpose chunk
#define TSTRIDE 136   // LDS row stride for GEMM transpose epilogues (bf16)
#define TSF 136       // LDS row stride for proj f32 transpose epilogue

#define N_WQ (2304 * 384)
#define N_WP (384 * 1536)
#define N_WD (384 * 9)
#define N_BI (NHEADS * NPIX * MPAD)

// flag-aware scalar load: f=1 -> fp32 data, f=0 -> bf16 data
__device__ __forceinline__ float ldf(const void* p, size_t i, int f) {
    return f ? ((const float*)p)[i] : (float)((const bf16*)p)[i];
}

// async global->LDS, 16B per lane. LDS dest must be wave-uniform base + lane*16.
__device__ __forceinline__ void gld16(const void* g, void* lds_wave_base) {
    __builtin_amdgcn_global_load_lds(
        (const __attribute__((address_space(1))) void*)(unsigned long long)g,
        (__attribute__((address_space(3))) void*)(unsigned long long)lds_wave_base,
        16, 0, 0);
}

// bijective chunked XCD swizzle (m204)
__device__ __forceinline__ int xcd_swizzle(int orig, int nwg) {
    int q = nwg >> 3, r = nwg & 7;
    int xcd = orig & 7, idx = orig >> 3;
    return (xcd < r ? xcd * (q + 1) : r * (q + 1) + (xcd - r) * q) + idx;
}

// K=16 bf16 MFMA: B-frag layout matches the in-register P layout of swapped QK^T.
__device__ __forceinline__ f32x4 mfma16(bf16x4 a, bf16x4 b, f32x4 c) {
#if __has_builtin(__builtin_amdgcn_mfma_f32_16x16x16bf16_1k)
    return __builtin_amdgcn_mfma_f32_16x16x16bf16_1k(
        __builtin_bit_cast(short4v, a), __builtin_bit_cast(short4v, b), c, 0, 0, 0);
#else
    asm volatile("v_mfma_f32_16x16x16_bf16 %0, %1, %2, %0" : "+v"(c) : "v"(a), "v"(b));
    return c;
#endif
}

__device__ __forceinline__ f32x4 vmax4(f32x4 a, f32x4 b) {
    f32x4 r;
    r[0] = fmaxf(a[0], b[0]);
    r[1] = fmaxf(a[1], b[1]);
    r[2] = fmaxf(a[2], b[2]);
    r[3] = fmaxf(a[3], b[3]);
    return r;
}

// ---------------- dtype detector ----------------
__global__ void detect_kernel(const unsigned int* __restrict__ x, int* __restrict__ flag) {
    __shared__ int cnt;
    if (threadIdx.x == 0) cnt = 0;
    __syncthreads();
    int c = 0;
#pragma unroll
    for (int k = 0; k < 8; k++) {
        unsigned int w = x[threadIdx.x * 8 + k];
        unsigned int e = (w >> 7) & 0xFFu;
        if (e > 200u) c++;
    }
    atomicAdd(&cnt, c);
    __syncthreads();
    if (threadIdx.x == 0) *flag = (cnt >= 16) ? 1 : 0;
}

// ---------------- fused prep: weight converts + bias gather + V-pad zero ----------------
__global__ void prep_kernel(const void* __restrict__ qkv_w, const void* __restrict__ proj_w,
                            const void* __restrict__ dw_w, const void* __restrict__ ab,
                            const int* __restrict__ idx, const int* __restrict__ flag,
                            bf16* __restrict__ wq, bf16* __restrict__ wp, bf16* __restrict__ wd,
                            float* __restrict__ biasf, bf16* __restrict__ vb, int nvpad) {
    int f = *flag;
    long t = (long)blockIdx.x * 256 + threadIdx.x;
    if (t < N_WQ) { wq[t] = (bf16)ldf(qkv_w, t, f); return; }
    t -= N_WQ;
    if (t < N_WP) { wp[t] = (bf16)ldf(proj_w, t, f); return; }
    t -= N_WP;
    if (t < N_WD) { wd[t] = (bf16)ldf(dw_w, t, f); return; }
    t -= N_WD;
    if (t < N_BI) {
        int h = (int)(t / (NPIX * MPAD));
        int rem = (int)(t - (long)h * (NPIX * MPAD));
        int n = rem / MPAD, m = rem - n * MPAD;
        biasf[t] = (m < NPIX) ? ldf(ab, h * NPIX + idx[n * NPIX + m], f) : -1e30f;
        return;
    }
    t -= N_BI;
    if (t < nvpad) {
        long r = t / 7, c = t - r * 7;
        *(unsigned long long*)(vb + r * MPAD + NPIX + c * 4) = 0ull;
    }
}

// ---------------- transpose x: (b, c, hw) -> (b, hw, c), canonical bf16 ----------------
__global__ void transpose_x_kernel(const void* __restrict__ x, const int* __restrict__ flag,
                                   bf16* __restrict__ xt, int b0) {
    __shared__ bf16 tile[32][33];
    int f = *flag;
    int b = blockIdx.z, gb = b0 + b;
    int c0 = blockIdx.y * 32;
    int hw0 = blockIdx.x * 32;
    int tx = threadIdx.x, ty = threadIdx.y;
    int hw = hw0 + tx, c = c0 + ty;
    if (hw < NPIX) tile[ty][tx] = (bf16)ldf(x, ((size_t)gb * CIN + c) * NPIX + hw, f);
    __syncthreads();
    int hw2 = hw0 + ty, c2 = c0 + tx;
    if (hw2 < NPIX) xt[((size_t)b * NPIX + hw2) * CIN + c2] = tile[tx][ty];
}

// ---------------- 128(M)x256(N) GEMM mainloop, K_STEP=32, dbuf + counted vmcnt ----------------
// Per-wave output 64x128 (wm=wave>>1, wn=wave&1): 12 ds_read_b128 feed 32 MFMA
// per step (0.375 reads/MFMA vs 0.5 at 64x64) -- 25% less LDS + staging traffic
// per FLOP at the SAME barrier-per-MFMA cadence as the verified r4 loop.
// Staging swizzle (r7-verified): src chunk (lane&3)^((lane>>3)&3), read slot
// grp^((row>>1)&3). smem: A dbuf [2][128*32] + B dbuf [2][256*32] = 48KB.
template <int K>
__device__ __forceinline__ void gemm_tile_w(const bf16* __restrict__ A, const bf16* __restrict__ B,
                                            bf16* smem, f32x4 acc[4][8]) {
    constexpr int NS = K / 32;
    const int ABUF = 128 * 32, BBUF = 256 * 32;
    int tid = threadIdx.x;
    int wave = tid >> 6, lane = tid & 63;
    int wm = wave >> 1, wn = wave & 1;
    int row = lane & 15, grp = lane >> 4;
    int sr = lane >> 2;                         // row within 16-row staging group
    int scg = (lane & 3) ^ ((lane >> 3) & 3);   // swizzled source chunk
    bf16* As = smem;
    bf16* Bs = smem + 2 * ABUF;
    const bf16* Aga = A + (size_t)(wave * 32 + sr) * K + scg * 8;
    const bf16* Bga = B + (size_t)(wave * 64 + sr) * K + scg * 8;
    int rs = (grp ^ ((row >> 1) & 3)) * 8;      // read slot offset (elements)

#define STAGEW(s, bi)                                                              \
    {                                                                              \
        bf16* Ad = As + (bi) * ABUF + (wave * 32) * 32;                            \
        bf16* Bd = Bs + (bi) * BBUF + (wave * 64) * 32;                            \
        _Pragma("unroll") for (int p = 0; p < 2; p++)                              \
            gld16(Aga + (size_t)(p * 16) * K + (s) * 32, Ad + p * 16 * 32);        \
        _Pragma("unroll") for (int p = 0; p < 4; p++)                              \
            gld16(Bga + (size_t)(p * 16) * K + (s) * 32, Bd + p * 16 * 32);        \
    }

    STAGEW(0, 0);
    int cur = 0;
#pragma unroll 1
    for (int s = 0; s < NS; s++) {
        if (s + 1 < NS) {
            STAGEW(s + 1, cur ^ 1);
            __builtin_amdgcn_sched_barrier(0);
            asm volatile("s_waitcnt vmcnt(6)" ::: "memory");  // drain step s only
        } else {
            __builtin_amdgcn_sched_barrier(0);
            asm volatile("s_waitcnt vmcnt(0)" ::: "memory");
        }
        __builtin_amdgcn_s_barrier();
        __builtin_amdgcn_sched_barrier(0);
        const bf16* Asc = As + cur * ABUF;
        const bf16* Bsc = Bs + cur * BBUF;
        bf16x8 af[4], bfr[8];
#pragma unroll
        for (int t = 0; t < 4; t++)
            af[t] = *(const bf16x8*)(Asc + (wm * 64 + t * 16 + row) * 32 + rs);
#pragma unroll
        for (int u = 0; u < 8; u++)
            bfr[u] = *(const bf16x8*)(Bsc + (wn * 128 + u * 16 + row) * 32 + rs);
#pragma unroll
        for (int mt = 0; mt < 4; mt++)
#pragma unroll
            for (int nt = 0; nt < 8; nt++)
                acc[mt][nt] =
                    __builtin_amdgcn_mfma_f32_16x16x32_bf16(af[mt], bfr[nt], acc[mt][nt], 0, 0, 0);
        __builtin_amdgcn_sched_barrier(0);
        __builtin_amdgcn_s_barrier();
        cur ^= 1;
    }
#undef STAGEW
    __builtin_amdgcn_sched_barrier(0);
}

// ---------------- QKV GEMM + BN, routed outputs via LDS-transpose (2 n-half passes) ----------------
__global__ __launch_bounds__(256, 2) void gemm_qkv_kernel(
    const bf16* __restrict__ xt, const bf16* __restrict__ w,
    const void* __restrict__ g, const void* __restrict__ bb,
    const void* __restrict__ mm, const void* __restrict__ vv, const int* __restrict__ flag,
    bf16* __restrict__ qb, bf16* __restrict__ kt, bf16* __restrict__ vb, int ntot) {
    __shared__ bf16 smem[2 * 128 * 32 + 2 * 256 * 32];  // 48KB; overlaid by tbuf after loop
    f32x4 acc[4][8];
#pragma unroll
    for (int i = 0; i < 4; i++)
#pragma unroll
        for (int j = 0; j < 8; j++) acc[i][j] = (f32x4){0.f, 0.f, 0.f, 0.f};
    int nwg = gridDim.x * gridDim.y;
    int l = xcd_swizzle(blockIdx.y * gridDim.x + blockIdx.x, nwg);
    int m0 = (l % gridDim.x) * 128, n0 = (l / gridDim.x) * 256;
    gemm_tile_w<CIN>(w + (size_t)m0 * CIN, xt + (size_t)n0 * CIN, smem, acc);
    int f = *flag;
    int tid = threadIdx.x;
    int wave = tid >> 6, lane = tid & 63;
    int wm = wave >> 1, wn = wave & 1, row = lane & 15, grp = lane >> 4;
    bf16* tbuf = smem;  // [128][TSTRIDE]
    if (m0 >= 384 && m0 < 768) {
        // k route: n-major [n][o]; kt row addr LINEAR in n (n*384).
#pragma unroll
        for (int half = 0; half < 2; half++) {
            if (wn == half) {
#pragma unroll
                for (int mt = 0; mt < 4; mt++) {
#pragma unroll
                    for (int r = 0; r < 4; r++) {
                        int ol = wm * 64 + mt * 16 + grp * 4 + r;
                        int o = m0 + ol;
                        float scv = ldf(g, o, f) * rsqrtf(ldf(vv, o, f) + 1e-5f);
                        float sh = ldf(bb, o, f) - ldf(mm, o, f) * scv;
#pragma unroll
                        for (int nt = 0; nt < 8; nt++) {
                            int nl = nt * 16 + row;
                            tbuf[nl * TSTRIDE + ol] = (bf16)(acc[mt][nt][r] * scv + sh);
                        }
                    }
                }
            }
            __syncthreads();
#pragma unroll
            for (int it = 0; it < 8; it++) {
                int g2 = it * 256 + tid;
                int nl = g2 >> 4, ch = g2 & 15;
                int n = n0 + half * 128 + nl;
                if (n < ntot)
                    *(bf16x8*)(kt + (size_t)n * CIN + (m0 - 384) + ch * 8) =
                        *(const bf16x8*)(tbuf + nl * TSTRIDE + ch * 8);
            }
            __syncthreads();
        }
    } else {
        // q / v routes: o-major [o][n]
        bool isq = (m0 < 384);
        bf16* dst = isq ? qb : vb;
        int ostride = isq ? NPIX : MPAD;
        int obase = isq ? m0 : (m0 - 768);
        int orow_mul = isq ? 384 : 1536;
#pragma unroll
        for (int half = 0; half < 2; half++) {
            if (wn == half) {
#pragma unroll
                for (int mt = 0; mt < 4; mt++) {
#pragma unroll
                    for (int r = 0; r < 4; r++) {
                        int ol = wm * 64 + mt * 16 + grp * 4 + r;
                        int o = m0 + ol;
                        float scv = ldf(g, o, f) * rsqrtf(ldf(vv, o, f) + 1e-5f);
                        float sh = ldf(bb, o, f) - ldf(mm, o, f) * scv;
#pragma unroll
                        for (int nt = 0; nt < 8; nt++) {
                            int nl = nt * 16 + row;
                            tbuf[ol * TSTRIDE + nl] = (bf16)(acc[mt][nt][r] * scv + sh);
                        }
                    }
                }
            }
            __syncthreads();
#pragma unroll
            for (int it = 0; it < 8; it++) {
                int g2 = it * 256 + tid;
                int ol = g2 >> 4, ch = g2 & 15;
                int o = obase + ol;
                int ng = n0 + half * 128 + ch * 8;
                int b0i = ng / NPIX, hw0 = ng - b0i * NPIX;
                const bf16* src = tbuf + ol * TSTRIDE + ch * 8;
                if (hw0 <= NPIX - 8 && ng + 8 <= ntot) {
                    bf16* d = dst + ((size_t)b0i * orow_mul + o) * ostride + hw0;
                    *(bf16x4*)d = *(const bf16x4*)src;
                    *(bf16x4*)(d + 4) = *(const bf16x4*)(src + 4);
                } else {
#pragma unroll
                    for (int j = 0; j < 8; j++) {
                        int n2 = ng + j;
                        if (n2 < ntot) {
                            int bj = n2 / NPIX, hwj = n2 - bj * NPIX;
                            dst[((size_t)bj * orow_mul + o) * ostride + hwj] = src[j];
                        }
                    }
                }
            }
            __syncthreads();
        }
    }
}

// ---------------- proj GEMM + BN -> output (f32 path via LDS-transpose, 4 passes) ----------------
__global__ __launch_bounds__(256, 2) void gemm_proj_kernel(
    const bf16* __restrict__ ot, const bf16* __restrict__ w,
    const void* __restrict__ g, const void* __restrict__ bb,
    const void* __restrict__ mm, const void* __restrict__ vv, const int* __restrict__ flag,
    void* __restrict__ out, int b0, int ntot) {
    __shared__ bf16 smem[2 * 128 * 32 + 2 * 256 * 32];
    f32x4 acc[4][8];
#pragma unroll
    for (int i = 0; i < 4; i++)
#pragma unroll
        for (int j = 0; j < 8; j++) acc[i][j] = (f32x4){0.f, 0.f, 0.f, 0.f};
    int nwg = gridDim.x * gridDim.y;
    int l = xcd_swizzle(blockIdx.y * gridDim.x + blockIdx.x, nwg);
    int m0 = (l % gridDim.x) * 128, n0 = (l / gridDim.x) * 256;
    gemm_tile_w<1536>(w + (size_t)m0 * 1536, ot + (size_t)n0 * 1536, smem, acc);
    int f = *flag;
    int tid = threadIdx.x;
    int wave = tid >> 6, lane = tid & 63;
    int wm = wave >> 1, wn = wave & 1, row = lane & 15, grp = lane >> 4;
    if (f) {
        float* tb = (float*)smem;   // [64][TSF] f32 = 34816B
#pragma unroll
        for (int oh = 0; oh < 2; oh++) {
#pragma unroll
            for (int nh = 0; nh < 2; nh++) {
                if (wm == oh && wn == nh) {
#pragma unroll
                    for (int mt = 0; mt < 4; mt++) {
#pragma unroll
                        for (int r = 0; r < 4; r++) {
                            int ol = mt * 16 + grp * 4 + r;
                            int o = m0 + oh * 64 + ol;
                            float scv = ldf(g, o, f) * rsqrtf(ldf(vv, o, f) + 1e-5f);
                            float sh = ldf(bb, o, f) - ldf(mm, o, f) * scv;
#pragma unroll
                            for (int nt = 0; nt < 8; nt++) {
                                int nl = nt * 16 + row;
                                tb[ol * TSF + nl] = acc[mt][nt][r] * scv + sh;
                            }
                        }
                    }
                }
                __syncthreads();
                float* outf = (float*)out;
#pragma unroll
                for (int it = 0; it < 8; it++) {
                    int g2 = it * 256 + tid;
                    int ol = g2 >> 5, ch = g2 & 31;
                    int o = m0 + oh * 64 + ol;
                    int ng = n0 + nh * 128 + ch * 4;
                    int b0i = ng / NPIX, hw0 = ng - b0i * NPIX;
                    const float* src = tb + ol * TSF + ch * 4;
                    if (hw0 <= NPIX - 4 && ng + 4 <= ntot) {
                        *(f32x4*)(outf + ((size_t)(b0 + b0i) * 384 + o) * NPIX + hw0) =
                            *(const f32x4*)src;
                    } else {
#pragma unroll
                        for (int j = 0; j < 4; j++) {
                            int n2 = ng + j;
                            if (n2 < ntot) {
                                int bj = n2 / NPIX, hwj = n2 - bj * NPIX;
                                outf[((size_t)(b0 + bj) * 384 + o) * NPIX + hwj] = src[j];
                            }
                        }
                    }
                }
                __syncthreads();
            }
        }
    } else {
        // bf16 output: scalar correctness path
#pragma unroll
        for (int mt = 0; mt < 4; mt++) {
#pragma unroll
            for (int r = 0; r < 4; r++) {
                int o = m0 + wm * 64 + mt * 16 + grp * 4 + r;
                float scv = ldf(g, o, f) * rsqrtf(ldf(vv, o, f) + 1e-5f);
                float sh = ldf(bb, o, f) - ldf(mm, o, f) * scv;
#pragma unroll
                for (int nt = 0; nt < 8; nt++) {
                    int n = n0 + wn * 128 + nt * 16 + row;
                    if (n < ntot) {
                        int b = n / NPIX, hw = n - b * NPIX;
                        ((bf16*)out)[((size_t)(b0 + b) * 384 + o) * NPIX + hw] =
                            (bf16)(acc[mt][nt][r] * scv + sh);
                    }
                }
            }
        }
    }
}

// ---------------- depthwise 3x3 conv + BN, write transposed (b, hw, c) ----------------
__global__ void dwconv_kernel(const bf16* __restrict__ qb, const bf16* __restrict__ w,
                              const void* __restrict__ g, const void* __restrict__ bb,
                              const void* __restrict__ mm, const void* __restrict__ vv,
                              const int* __restrict__ flag, bf16* __restrict__ qt) {
    __shared__ bf16 tile[32][33];
    int f = *flag;
    int b = blockIdx.z;
    int c0 = blockIdx.y * 32, hw0 = blockIdx.x * 32;
    int tx = threadIdx.x, ty = threadIdx.y;
    int c = c0 + ty, hw = hw0 + tx;
    if (hw < NPIX) {
        int y = hw / 14, x = hw % 14;
        float acc = 0.f;
        const bf16* wp = w + c * 9;
        const bf16* qp = qb + ((size_t)b * 384 + c) * NPIX;
#pragma unroll
        for (int ky = 0; ky < 3; ky++) {
            int yy = y + ky - 1;
            if (yy < 0 || yy >= 14) continue;
#pragma unroll
            for (int kx = 0; kx < 3; kx++) {
                int xx = x + kx - 1;
                if (xx < 0 || xx >= 14) continue;
                acc += (float)qp[yy * 14 + xx] * (float)wp[ky * 3 + kx];
            }
        }
        float sc = ldf(g, c, f) * rsqrtf(ldf(vv, c, f) + 1e-5f);
        float sh = ldf(bb, c, f) - ldf(mm, c, f) * sc;
        tile[ty][tx] = (bf16)(acc * sc + sh);
    }
    __syncthreads();
    int hw2 = hw0 + ty, c2 = c0 + tx;
    if (hw2 < NPIX) qt[((size_t)b * NPIX + hw2) * CIN + c2] = tile[tx][ty];
}

// ---------------- attention per (b,h) ----------------
__global__ __launch_bounds__(256, 2) void attn_kernel(
    const bf16* __restrict__ qt, const bf16* __restrict__ ktp, const bf16* __restrict__ vb,
    const float* __restrict__ biasf, bf16* __restrict__ ot) {
    __shared__ bf16 Vs[128 * VSTRIDE];          // 59392 B
    __shared__ bf16 Osh[4][16 * OSTRIDE];       // 5120 B
    int nwg = gridDim.x * gridDim.y;
    int l = xcd_swizzle(blockIdx.y * gridDim.x + blockIdx.x, nwg);
    int h = l % NHEADS, b = l / NHEADS;
    int tid = threadIdx.x;
    int wave = tid >> 6, lane = tid & 63;
    int row = lane & 15, grp = lane >> 4;
    const float scale = 0.17677669529663687f;
    const f32x4 zf = {0.f, 0.f, 0.f, 0.f};

    {
        const bf16* vsrc = vb + ((size_t)b * 1536 + h * 128) * MPAD;
#pragma unroll
        for (int it = 0; it < 14; it++) {
            int i = it * 256 + tid;
            int r = i / 28, gch = i - r * 28;
            *(bf16x8*)(Vs + r * VSTRIDE + gch * 8) = *(const bf16x8*)(vsrc + (size_t)i * 8);
        }
    }
    __syncthreads();

    const bf16* vls = Vs + row * VSTRIDE + grp * 4;

    for (int nb = wave; nb < 13; nb += 4) {
        int n0 = nb * 16;
        int n = n0 + row;
        int nc = n > 195 ? 195 : n;

        bf16x8 aq = *(const bf16x8*)(qt + ((size_t)b * NPIX + nc) * CIN + h * 32 + grp * 8);

        f32x4 sacc[14];
        __builtin_amdgcn_s_setprio(1);
#pragma unroll
        for (int mt = 0; mt < 14; mt++) {
            int krow = mt * 16 + row;
            if (krow > 195) krow = 195;
            bf16x8 ak = *(const bf16x8*)(ktp + ((size_t)b * NPIX + krow) * CIN + h * 32 + grp * 8);
            sacc[mt] = __builtin_amdgcn_mfma_f32_16x16x32_bf16(ak, aq, zf, 0, 0, 0);
        }
        __builtin_amdgcn_s_setprio(0);

        const float* bp = biasf + ((size_t)h * NPIX + nc) * MPAD + grp * 4;
        f32x4 mxv = {-3.4e38f, -3.4e38f, -3.4e38f, -3.4e38f};
#pragma unroll
        for (int mt = 0; mt < 14; mt++) {
            f32x4 bv = *(const f32x4*)(bp + mt * 16);
            f32x4 s = sacc[mt] * scale + bv;
            sacc[mt] = s;
            mxv = vmax4(mxv, s);
        }
        float mx = fmaxf(fmaxf(mxv[0], mxv[1]), fmaxf(mxv[2], mxv[3]));
        mx = fmaxf(mx, __shfl_xor(mx, 16));
        mx = fmaxf(mx, __shfl_xor(mx, 32));

        f32x4 sumv = zf;
        bf16x4 pf[14];
#pragma unroll
        for (int mt = 0; mt < 14; mt++) {
            f32x4 e;
#pragma unroll
            for (int r = 0; r < 4; r++) e[r] = __expf(sacc[mt][r] - mx);
            sumv += e;
            bf16x4 pb;
#pragma unroll
            for (int r = 0; r < 4; r++) pb[r] = (bf16)e[r];
            pf[mt] = pb;
        }
        float sum = (sumv[0] + sumv[1]) + (sumv[2] + sumv[3]);
        sum += __shfl_xor(sum, 16);
        sum += __shfl_xor(sum, 32);
        float inv = 1.f / sum;

        f32x4 oacc[8];
#pragma unroll
        for (int dt = 0; dt < 8; dt++) oacc[dt] = zf;
        __builtin_amdgcn_s_setprio(1);
#pragma unroll
        for (int mt = 0; mt < 14; mt++) {
            bf16x4 p = pf[mt];
#pragma unroll
            for (int dt = 0; dt < 8; dt++) {
                bf16x4 v4 = *(const bf16x4*)(vls + dt * 16 * VSTRIDE + mt * 16);
                oacc[dt] = mfma16(v4, p, oacc[dt]);
            }
        }
        __builtin_amdgcn_s_setprio(0);

        bf16* osw = Osh[wave];
        int r2 = lane >> 2, c2 = lane & 3;
        int n2 = n0 + r2;
        bf16* op = ot + ((size_t)b * NPIX + n2) * 1536 + h * 128;
#pragma unroll
        for (int dp = 0; dp < 4; dp++) {
#pragma unroll
            for (int u = 0; u < 2; u++) {
                int dt = dp * 2 + u;
                bf16x4 o4;
#pragma unroll
                for (int r = 0; r < 4; r++) {
                    float v = oacc[dt][r] * inv;
                    o4[r] = (bf16)(v > 0.f ? v : 0.f);
                }
                *(bf16x4*)(osw + row * OSTRIDE + u * 16 + grp * 4) = o4;
            }
            asm volatile("s_waitcnt lgkmcnt(0)" ::: "memory");
            if (n2 < NPIX) {
                bf16x8 ov = *(const bf16x8*)(osw + r2 * OSTRIDE + c2 * 8);
                *(bf16x8*)(op + dp * 32 + c2 * 8) = ov;
            }
            asm volatile("s_waitcnt lgkmcnt(0)" ::: "memory");
        }
    }
}

extern "C" void kernel_launch(void* const* d_in, const int* in_sizes, int n_in,
                              void* d_out, int out_size, void* d_ws, size_t ws_size,
                              hipStream_t stream) {
    const void* x      = d_in[0];
    const void* qkv_w  = d_in[1];
    const void* qkv_g  = d_in[2];
    const void* qkv_b  = d_in[3];
    const void* qkv_m  = d_in[4];
    const void* qkv_v  = d_in[5];
    const void* dw_w   = d_in[6];
    const void* dw_g   = d_in[7];
    const void* dw_b   = d_in[8];
    const void* dw_m   = d_in[9];
    const void* dw_v   = d_in[10];
    const void* proj_w = d_in[11];
    const void* proj_g = d_in[12];
    const void* proj_b = d_in[13];
    const void* proj_m = d_in[14];
    const void* proj_v = d_in[15];
    const void* ab     = d_in[16];
    const int*  idx    = (const int*)d_in[17];

    char* ws = (char*)d_ws;
    size_t off = 0;
    auto alloc = [&](size_t bytes) { void* p = ws + off; off += (bytes + 255) & ~(size_t)255; return p; };

    int*   flag = (int*)alloc(4);
    bf16*  wq   = (bf16*)alloc((size_t)N_WQ * 2);
    bf16*  wp   = (bf16*)alloc((size_t)N_WP * 2);
    bf16*  wd   = (bf16*)alloc((size_t)N_WD * 2);
    float* biasf= (float*)alloc((size_t)N_BI * 4);
    size_t fixed = off;

    const size_t s_xt = (size_t)NPIX * CIN;
    const size_t s_qb = (size_t)384 * NPIX;
    const size_t s_kt = (size_t)NPIX * 384;
    const size_t s_vb = (size_t)1536 * MPAD;
    const size_t s_ot = (size_t)NPIX * 1536;
    const size_t per_image = (s_xt + s_qb + s_kt + s_vb + s_ot) * 2;

    int CB = 128;
    while (CB > 32 && fixed + (size_t)CB * per_image > ws_size) CB >>= 1;

    bf16* xt  = (bf16*)alloc((size_t)CB * s_xt * 2);
    bf16* qb  = (bf16*)alloc((size_t)CB * s_qb * 2);
    bf16* ktp = (bf16*)alloc((size_t)CB * s_kt * 2);
    bf16* vb  = (bf16*)alloc((size_t)CB * s_vb * 2);
    bf16* ot  = (bf16*)alloc((size_t)CB * s_ot * 2);
    bf16* qt  = xt;  // xt dead after gemm_qkv; reuse for dwconv output

    detect_kernel<<<dim3(1), dim3(256), 0, stream>>>((const unsigned int*)x, flag);
    int nvpad = CB * 1536 * 7;
    long prep_total = (long)N_WQ + N_WP + N_WD + N_BI + nvpad;
    int prep_blocks = (int)((prep_total + 255) / 256);
    prep_kernel<<<dim3(prep_blocks), dim3(256), 0, stream>>>(qkv_w, proj_w, dw_w, ab, idx, flag,
                                                             wq, wp, wd, biasf, vb, nvpad);

    dim3 tb(32, 32);
    for (int b0 = 0; b0 < 128; b0 += CB) {
        int cb = (128 - b0 < CB) ? (128 - b0) : CB;
        int ntot = cb * NPIX;
        int ntiles = (ntot + 255) / 256;
        transpose_x_kernel<<<dim3(7, 12, cb), tb, 0, stream>>>(x, flag, xt, b0);
        gemm_qkv_kernel<<<dim3(18, ntiles), dim3(256), 0, stream>>>(xt, wq, qkv_g, qkv_b, qkv_m,
                                                                    qkv_v, flag, qb, ktp, vb, ntot);
        dwconv_kernel<<<dim3(7, 12, cb), tb, 0, stream>>>(qb, wd, dw_g, dw_b, dw_m, dw_v, flag, qt);
        attn_kernel<<<dim3(NHEADS, cb), dim3(256), 0, stream>>>(qt, ktp, vb, biasf, ot);
        gemm_proj_kernel<<<dim3(3, ntiles), dim3(256), 0, stream>>>(ot, wp, proj_g, proj_b, proj_m,
                                                                    proj_v, flag, d_out, b0, ntot);
    }
}